// Round 6
// baseline (462.091 us; speedup 1.0000x reference)
//
#include <hip/hip_runtime.h>
#include <hip/hip_bf16.h>

#define T_ 256
#define B_ 16
#define S_ 64
#define D_ 256

typedef __attribute__((ext_vector_type(4))) int int4v;

__device__ __forceinline__ float tanh_fast(float x) {
    // tanh(x) = 1 - 2/(1+exp(2x)); saturates correctly at +-inf
    float e = __expf(2.0f * x);
    float r = __builtin_amdgcn_rcpf(e + 1.0f);
    return __builtin_fmaf(-2.0f, r, 1.0f);
}

// ---------------- W_x transpose: WxT[k][d] = W_x[d][k] ----------------
__global__ void k_transpose(const float* __restrict__ in, float* __restrict__ out) {
    __shared__ float tile[32][33];
    int tx = threadIdx.x & 31, ty = threadIdx.x >> 5;
    int bx = blockIdx.x & 7, by = blockIdx.x >> 3;
    tile[ty][tx] = in[(by * 32 + ty) * D_ + bx * 32 + tx];
    __syncthreads();
    out[(bx * 32 + ty) * D_ + by * 32 + tx] = tile[tx][ty];
}

// -------- Wxall[t*B+b][d] = bias[d] + sum_k x[t,b,k] * WxT[k][d] --------
__global__ __launch_bounds__(256) void k_wxall(const float* __restrict__ x,
                                               const float* __restrict__ WxT,
                                               const float* __restrict__ bias,
                                               float* __restrict__ wxall) {
    __shared__ float xs[16][D_];
    const int tid = threadIdx.x;
    const int row0 = blockIdx.x * 16;
    for (int r = 0; r < 16; ++r)
        xs[r][tid] = x[(size_t)(row0 + r) * D_ + tid];
    __syncthreads();
    float acc[16];
    float bv = bias[tid];
#pragma unroll
    for (int r = 0; r < 16; ++r) acc[r] = bv;
    for (int k = 0; k < D_; ++k) {
        float wv = WxT[k * D_ + tid];
#pragma unroll
        for (int r = 0; r < 16; ++r) acc[r] = __builtin_fmaf(wv, xs[r][k], acc[r]);
    }
    for (int r = 0; r < 16; ++r)
        wxall[(size_t)(row0 + r) * D_ + tid] = acc[r];
}

// ---------------- main recurrence (i8 MFMA K=64, 2 slots/block) ----------------
// grid = 512 blocks: block -> (b = blk>>5, slots {s0, s0+1}, s0 = (blk&31)*2)
// block = 512 threads = 8 waves; __launch_bounds__(512,4) => 2 blocks/CU, so a
// co-resident INDEPENDENT block fills this block's barrier/latency gaps.
// wave w owns n-slice [32w, 32w+32). Thread: d = 32w + (lane&31),
// slot = (quad>>1)&1 (A rows replicate m&1 -> C reg parity = slot, any quad).
__global__ __launch_bounds__(512, 4) void k_rec(
    const float* __restrict__ Wh,      // [D][D] (n-major: Wh[n][k])
    const float* __restrict__ wxall,   // [T*B][D], bias folded in
    const float* __restrict__ z,       // [T*B][D]
    const float* __restrict__ h0,      // [B][S][D]
    const float* __restrict__ Cvec,    // [S]
    float* __restrict__ outputs,       // [T*B][D], pre-zeroed (atomic accum)
    float* __restrict__ h_out)         // [(T+1)*B][S][D]
{
    const int tid  = threadIdx.x;
    const int w    = tid >> 6;
    const int lane = tid & 63;
    const int l16  = lane & 15;
    const int quad = lane >> 4;
    const int b    = blockIdx.x >> 5;
    const int s0   = (blockIdx.x & 31) * 2;
    const int slot = (quad >> 1) & 1;          // this thread's slot
    const int d    = (w << 5) | (lane & 31);   // this thread's output column

    // ping-pong h buffer, i8, 2 rows. Row stride 288 B keeps the 8 distinct
    // b128 A-chunks at worst 2-way per bank (free, m136).
    __shared__ __align__(16) signed char hA8[2][2][288];

    // init hA8[0] from h0 and write h[0] = h0  (512 threads = exactly 2*256)
    {
        int r = tid >> 8, dd = tid & 255;
        float v = h0[(size_t)(b * S_ + s0 + r) * D_ + dd];
        float vc = fminf(fmaxf(v, -1.0f), 1.0f);
        hA8[0][r][dd] = (signed char)__float2int_rn(vc * 127.0f);
        h_out[(size_t)(b * S_ + s0 + r) * D_ + dd] = v;
    }

    // ---- pass 1: per-column absmax of Wh for cols n = 32w + nt*16 + l16 ----
    // lane scans k = kt*64 + quad*16 + {0..15}; shfl_xor over lane bits 4,5
    // combines the quads into the full-column max.
    float cmax[2];
#pragma unroll
    for (int nt = 0; nt < 2; ++nt) {
        const float* wr = Wh + (size_t)(w * 32 + nt * 16 + l16) * D_ + quad * 16;
        float cm = 1e-20f;
#pragma unroll
        for (int kt = 0; kt < 4; ++kt) {
            const float* p = wr + kt * 64;
#pragma unroll
            for (int j = 0; j < 16; j += 4) {
                float4 v = *(const float4*)(p + j);
                cm = fmaxf(cm, fmaxf(fmaxf(fabsf(v.x), fabsf(v.y)),
                                     fmaxf(fabsf(v.z), fabsf(v.w))));
            }
        }
        cm = fmaxf(cm, __shfl_xor(cm, 16, 64));
        cm = fmaxf(cm, __shfl_xor(cm, 32, 64));
        cmax[nt] = cm;
    }

    // ---- pass 2: quantize Wh -> i8 B-fragments (32 VGPRs) ----
    // lane holds B[k = kt*64 + quad*16 + j][n = 32w + nt*16 + l16]
    int4v Bf[4][2];
#pragma unroll
    for (int nt = 0; nt < 2; ++nt) {
        const float rs = 127.0f / cmax[nt];
        const float* wr = Wh + (size_t)(w * 32 + nt * 16 + l16) * D_ + quad * 16;
#pragma unroll
        for (int kt = 0; kt < 4; ++kt) {
            const float* p = wr + kt * 64;
            int4v frag;
#pragma unroll
            for (int r = 0; r < 4; ++r) {
                float4 v = *(const float4*)(p + r * 4);
                int q0 = __float2int_rn(v.x * rs) & 255;
                int q1 = __float2int_rn(v.y * rs) & 255;
                int q2 = __float2int_rn(v.z * rs) & 255;
                int q3 = __float2int_rn(v.w * rs) & 255;
                frag[r] = q0 | (q1 << 8) | (q2 << 16) | (q3 << 24);
            }
            Bf[kt][nt] = frag;
        }
    }
    // this thread's output-column dequant scale: col d -> nt = quad&1
    const float dscale = ((quad & 1) ? cmax[1] : cmax[0]) * (1.0f / 16129.0f);
    const float cq = Cvec[s0 + slot];
    __syncthreads();

    float wx = wxall[(unsigned)b * D_ + d];   // t=0 row
    float zv = z[(unsigned)b * D_ + d];

    // running output offsets
    unsigned hb = (unsigned)(1 * B_ + b) * (S_ * D_) + (unsigned)(s0 + slot) * D_ + d;
    unsigned ob = (unsigned)b * D_ + d;

    // 2-deep deferred global stores (parity = t&1), flushed at t+2 so the
    // pre-barrier vmcnt drain never waits on a fresh HBM store/atomic.
    float dh_0, dos_0; unsigned dhb_0, dob_0;
    float dh_1, dos_1; unsigned dhb_1, dob_1;

#define STEP(t, CUR, NXT)                                                      \
    {                                                                          \
        const signed char* ap = &hA8[CUR][l16 & 1][quad * 16];                 \
        int4v Af0 = *(const int4v*)(ap);                                       \
        int4v Af1 = *(const int4v*)(ap + 64);                                  \
        int4v Af2 = *(const int4v*)(ap + 128);                                 \
        int4v Af3 = *(const int4v*)(ap + 192);                                 \
        if ((t) >= 2) { /* flush step t-2 (same parity) */                     \
            __builtin_nontemporal_store(dh_##CUR, h_out + dhb_##CUR);          \
            if (quad < 2) atomicAdd(outputs + dob_##CUR, dos_##CUR);           \
        }                                                                      \
        const int tn = ((t) + 1 < T_) ? (t) + 1 : (t);                         \
        float wx_n = wxall[(unsigned)(tn * B_ + b) * D_ + d];                  \
        float zv_n = z[(unsigned)(tn * B_ + b) * D_ + d];                      \
        int4v acc0 = {0, 0, 0, 0}, acc1 = acc0;                                \
        acc0 = __builtin_amdgcn_mfma_i32_16x16x64_i8(Af0, Bf[0][0], acc0, 0, 0, 0); \
        acc1 = __builtin_amdgcn_mfma_i32_16x16x64_i8(Af0, Bf[0][1], acc1, 0, 0, 0); \
        acc0 = __builtin_amdgcn_mfma_i32_16x16x64_i8(Af1, Bf[1][0], acc0, 0, 0, 0); \
        acc1 = __builtin_amdgcn_mfma_i32_16x16x64_i8(Af1, Bf[1][1], acc1, 0, 0, 0); \
        acc0 = __builtin_amdgcn_mfma_i32_16x16x64_i8(Af2, Bf[2][0], acc0, 0, 0, 0); \
        acc1 = __builtin_amdgcn_mfma_i32_16x16x64_i8(Af2, Bf[2][1], acc1, 0, 0, 0); \
        acc0 = __builtin_amdgcn_mfma_i32_16x16x64_i8(Af3, Bf[3][0], acc0, 0, 0, 0); \
        acc1 = __builtin_amdgcn_mfma_i32_16x16x64_i8(Af3, Bf[3][1], acc1, 0, 0, 0); \
        /* C reg parity = slot (A rows replicate m&1); nt select by quad&1 */  \
        int va = (quad & 1) ? acc1[0] : acc0[0];                               \
        int vb = (quad & 1) ? acc1[1] : acc0[1];                               \
        int vi = (quad & 2) ? vb : va;                                         \
        float hv = tanh_fast(__builtin_fmaf((float)vi, dscale, wx));           \
        hA8[NXT][slot][d] = (signed char)__float2int_rn(hv * 127.0f);          \
        float sig  = __builtin_amdgcn_rcpf(1.0f + __expf(-zv));                \
        float part = cq * hv;                                                  \
        part += __shfl_xor(part, 32, 64);  /* slot0 + slot1 for col d */       \
        dh_##CUR  = hv;                                                        \
        dhb_##CUR = hb; hb += (unsigned)(B_ * S_ * D_);                        \
        dob_##CUR = ob; ob += (unsigned)(B_ * D_);                             \
        dos_##CUR = part * (zv * sig);                                         \
        wx = wx_n; zv = zv_n;                                                  \
        __syncthreads();                                                       \
    }

    for (int t2 = 0; t2 < T_; t2 += 2) {
        STEP(t2, 0, 1)
        STEP(t2 + 1, 1, 0)
    }
#undef STEP

    // tail: flush the last two steps
    __builtin_nontemporal_store(dh_0, h_out + dhb_0);
    if (quad < 2) atomicAdd(outputs + dob_0, dos_0);
    __builtin_nontemporal_store(dh_1, h_out + dhb_1);
    if (quad < 2) atomicAdd(outputs + dob_1, dos_1);
}

extern "C" void kernel_launch(void* const* d_in, const int* in_sizes, int n_in,
                              void* d_out, int out_size, void* d_ws, size_t ws_size,
                              hipStream_t stream) {
    const float* x    = (const float*)d_in[0];
    const float* z    = (const float*)d_in[1];
    const float* h0   = (const float*)d_in[2];
    const float* W_x  = (const float*)d_in[3];
    const float* W_h  = (const float*)d_in[4];
    const float* bias = (const float*)d_in[5];
    const float* C    = (const float*)d_in[6];

    float* outputs = (float*)d_out;                     // [T*B*D]
    float* h_out   = outputs + (size_t)T_ * B_ * D_;    // [(T+1)*B*S*D]

    float* WxT   = (float*)d_ws;                        // D*D floats
    float* wxall = WxT + D_ * D_;                       // T*B*D floats

    hipMemsetAsync(outputs, 0, (size_t)T_ * B_ * D_ * sizeof(float), stream);
    k_transpose<<<64, 1024, 0, stream>>>(W_x, WxT);
    k_wxall<<<T_ * B_ / 16, 256, 0, stream>>>(x, WxT, bias, wxall);
    k_rec<<<B_ * S_ / 2, 512, 0, stream>>>(W_h, wxall, z, h0, C, outputs, h_out);
}

// Round 7
// 378.784 us; speedup vs baseline: 1.2199x; 1.2199x over previous
//
#include <hip/hip_runtime.h>
#include <hip/hip_bf16.h>

#define T_ 256
#define B_ 16
#define S_ 64
#define D_ 256

typedef __attribute__((ext_vector_type(4))) int int4v;

__device__ __forceinline__ float tanh_fast(float x) {
    // tanh(x) = 1 - 2/(1+exp(2x)); saturates correctly at +-inf
    float e = __expf(2.0f * x);
    float r = __builtin_amdgcn_rcpf(e + 1.0f);
    return __builtin_fmaf(-2.0f, r, 1.0f);
}

// LDS-visibility-only barrier: waits DS ops, leaves global loads/stores/atomics
// in flight across the barrier (the __syncthreads vmcnt(0) drain was costing
// ~600 cyc/step of exposed HBM latency).
#define LDS_BARRIER() asm volatile("s_waitcnt lgkmcnt(0)\n\ts_barrier" ::: "memory")

// ---------------- W_x transpose: WxT[k][d] = W_x[d][k] ----------------
__global__ void k_transpose(const float* __restrict__ in, float* __restrict__ out) {
    __shared__ float tile[32][33];
    int tx = threadIdx.x & 31, ty = threadIdx.x >> 5;
    int bx = blockIdx.x & 7, by = blockIdx.x >> 3;
    tile[ty][tx] = in[(by * 32 + ty) * D_ + bx * 32 + tx];
    __syncthreads();
    out[(bx * 32 + ty) * D_ + by * 32 + tx] = tile[tx][ty];
}

// ---- wz[t*B+b][d] = { bias[d] + sum_k x[t,b,k]*WxT[k][d],  silu(z[t,b,d]) } ----
__global__ __launch_bounds__(256) void k_wxall(const float* __restrict__ x,
                                               const float* __restrict__ z,
                                               const float* __restrict__ WxT,
                                               const float* __restrict__ bias,
                                               float2* __restrict__ wz) {
    __shared__ float xs[16][D_];
    const int tid = threadIdx.x;
    const int row0 = blockIdx.x * 16;
    for (int r = 0; r < 16; ++r)
        xs[r][tid] = x[(size_t)(row0 + r) * D_ + tid];
    __syncthreads();
    float acc[16];
    float bv = bias[tid];
#pragma unroll
    for (int r = 0; r < 16; ++r) acc[r] = bv;
    for (int k = 0; k < D_; ++k) {
        float wv = WxT[k * D_ + tid];
#pragma unroll
        for (int r = 0; r < 16; ++r) acc[r] = __builtin_fmaf(wv, xs[r][k], acc[r]);
    }
    for (int r = 0; r < 16; ++r) {
        float zv = z[(size_t)(row0 + r) * D_ + tid];
        float sil = zv * __builtin_amdgcn_rcpf(1.0f + __expf(-zv));
        wz[(size_t)(row0 + r) * D_ + tid] = make_float2(acc[r], sil);
    }
}

// ---------------- main recurrence (i8 MFMA K=64, 4 slots/block) ----------------
// grid = 256 blocks: block -> (b = blk>>4, slots s0..s0+3, s0 = (blk&15)*4)
// block = 512 threads = 8 waves (2/SIMD); wave w owns n-slice [32w, 32w+32)
// Epilogue: lane -> col d = 32w + (lane&31); quad&1 = n-tile, quad&2 = slot-pair.
__global__ __launch_bounds__(512, 1) void k_rec(
    const float* __restrict__ Wh,      // [D][D] (n-major: Wh[n][k])
    const float2* __restrict__ wz,     // [T*B][D] {wx+bias, silu(z)}
    const float* __restrict__ h0,      // [B][S][D]
    const float* __restrict__ Cvec,    // [S]
    float* __restrict__ outputs,       // [T*B][D], pre-zeroed (atomic accum)
    float* __restrict__ h_out)         // [(T+1)*B][S][D]
{
    const int tid  = threadIdx.x;
    const int w    = tid >> 6;
    const int lane = tid & 63;
    const int l16  = lane & 15;
    const int quad = lane >> 4;
    const int b    = blockIdx.x >> 4;
    const int s0   = (blockIdx.x & 15) * 4;
    const int r0   = quad & 2;                 // slot-pair this thread finalizes
    const int d    = (w << 5) | (lane & 31);   // this thread's output column

    // ping-pong h buffer, i8. Row stride 288 B: the 16 distinct b128 A-chunks
    // land 2-way per bank (free, m136).
    __shared__ __align__(16) signed char hA8[2][4][288];

    // init hA8[0] from h0 and write h[0] = h0  (512 threads = 2*256 lanes)
    for (int i = tid; i < 4 * D_; i += 512) {
        int r = i >> 8, dd = i & 255;
        float v = h0[(size_t)(b * S_ + s0 + r) * D_ + dd];
        float vc = fminf(fmaxf(v, -1.0f), 1.0f);
        hA8[0][r][dd] = (signed char)__float2int_rn(vc * 127.0f);
        h_out[(size_t)(b * S_ + s0 + r) * D_ + dd] = v;
    }

    // ---- pass 1: per-column absmax of Wh for cols n = 32w + nt*16 + l16 ----
    float cmax[2];
#pragma unroll
    for (int nt = 0; nt < 2; ++nt) {
        const float* wr = Wh + (size_t)(w * 32 + nt * 16 + l16) * D_ + quad * 16;
        float cm = 1e-20f;
#pragma unroll
        for (int kt = 0; kt < 4; ++kt) {
            const float* p = wr + kt * 64;
#pragma unroll
            for (int j = 0; j < 16; j += 4) {
                float4 v = *(const float4*)(p + j);
                cm = fmaxf(cm, fmaxf(fmaxf(fabsf(v.x), fabsf(v.y)),
                                     fmaxf(fabsf(v.z), fabsf(v.w))));
            }
        }
        cm = fmaxf(cm, __shfl_xor(cm, 16, 64));
        cm = fmaxf(cm, __shfl_xor(cm, 32, 64));
        cmax[nt] = cm;
    }

    // ---- pass 2: quantize Wh -> i8 B-fragments (32 VGPRs) ----
    // lane holds B[k = kt*64 + quad*16 + j][n = 32w + nt*16 + l16]
    int4v Bf[4][2];
#pragma unroll
    for (int nt = 0; nt < 2; ++nt) {
        const float rs = 127.0f / cmax[nt];
        const float* wr = Wh + (size_t)(w * 32 + nt * 16 + l16) * D_ + quad * 16;
#pragma unroll
        for (int kt = 0; kt < 4; ++kt) {
            const float* p = wr + kt * 64;
            int4v frag;
#pragma unroll
            for (int r = 0; r < 4; ++r) {
                float4 v = *(const float4*)(p + r * 4);
                int q0 = __float2int_rn(v.x * rs) & 255;
                int q1 = __float2int_rn(v.y * rs) & 255;
                int q2 = __float2int_rn(v.z * rs) & 255;
                int q3 = __float2int_rn(v.w * rs) & 255;
                frag[r] = q0 | (q1 << 8) | (q2 << 16) | (q3 << 24);
            }
            Bf[kt][nt] = frag;
        }
    }
    const float dscale = ((quad & 1) ? cmax[1] : cmax[0]) * (1.0f / 16129.0f);
    const float c0 = Cvec[s0 + r0], c1 = Cvec[s0 + r0 + 1];

    // prologue: wz for t=0 and t=1; running pointers
    const float2* wzp = wz + (size_t)b * D_ + d;
    float2 wzr[2];
    wzr[0] = wzp[0];
    wzr[1] = wzp[(size_t)B_ * D_];
    wzp += (size_t)2 * B_ * D_;                 // points at t=2's row

    float* hp = h_out + (size_t)(1 * B_ + b) * (S_ * D_) + (size_t)(s0 + r0) * D_ + d;
    float* op = outputs + (size_t)b * D_ + d;

    __syncthreads();   // full barrier once (init visibility incl. global)

#define STEP(t, CUR, NXT)                                                      \
    {                                                                          \
        const signed char* ap = &hA8[CUR][l16 & 3][quad * 16];                 \
        int4v Af0 = *(const int4v*)(ap);                                       \
        int4v Af1 = *(const int4v*)(ap + 64);                                  \
        int4v Af2 = *(const int4v*)(ap + 128);                                 \
        int4v Af3 = *(const int4v*)(ap + 192);                                 \
        float wx  = wzr[CUR].x;                                                \
        float sil = wzr[CUR].y;                                                \
        wzr[CUR] = *wzp;                      /* load for t+2, 2-step cover */ \
        wzp += ((t) < T_ - 2) ? (size_t)B_ * D_ : 0;                           \
        int4v acc0 = {0, 0, 0, 0}, acc1 = acc0;                                \
        acc0 = __builtin_amdgcn_mfma_i32_16x16x64_i8(Af0, Bf[0][0], acc0, 0, 0, 0); \
        acc1 = __builtin_amdgcn_mfma_i32_16x16x64_i8(Af0, Bf[0][1], acc1, 0, 0, 0); \
        acc0 = __builtin_amdgcn_mfma_i32_16x16x64_i8(Af1, Bf[1][0], acc0, 0, 0, 0); \
        acc1 = __builtin_amdgcn_mfma_i32_16x16x64_i8(Af1, Bf[1][1], acc1, 0, 0, 0); \
        acc0 = __builtin_amdgcn_mfma_i32_16x16x64_i8(Af2, Bf[2][0], acc0, 0, 0, 0); \
        acc1 = __builtin_amdgcn_mfma_i32_16x16x64_i8(Af2, Bf[2][1], acc1, 0, 0, 0); \
        acc0 = __builtin_amdgcn_mfma_i32_16x16x64_i8(Af3, Bf[3][0], acc0, 0, 0, 0); \
        acc1 = __builtin_amdgcn_mfma_i32_16x16x64_i8(Af3, Bf[3][1], acc1, 0, 0, 0); \
        /* C rows quad-replicated (A rows m>=4 duplicate m&3): selects only */ \
        int ia = (quad & 2) ? acc0[2] : acc0[0];                               \
        int ib = (quad & 2) ? acc0[3] : acc0[1];                               \
        int ja = (quad & 2) ? acc1[2] : acc1[0];                               \
        int jb = (quad & 2) ? acc1[3] : acc1[1];                               \
        int sa = (quad & 1) ? ja : ia;                                         \
        int sb = (quad & 1) ? jb : ib;                                         \
        float hv0 = tanh_fast(__builtin_fmaf((float)sa, dscale, wx));          \
        float hv1 = tanh_fast(__builtin_fmaf((float)sb, dscale, wx));          \
        hA8[NXT][r0][d]     = (signed char)__float2int_rn(hv0 * 127.0f);       \
        hA8[NXT][r0 + 1][d] = (signed char)__float2int_rn(hv1 * 127.0f);       \
        __builtin_nontemporal_store(hv0, hp);                                  \
        __builtin_nontemporal_store(hv1, hp + D_);                             \
        hp += B_ * S_ * D_;                                                    \
        float part = __builtin_fmaf(c0, hv0, c1 * hv1);                        \
        part += __shfl_xor(part, 32, 64);   /* combine slot-pairs for col d */ \
        if (quad < 2) atomicAdd(op, part * sil);                               \
        op += B_ * D_;                                                         \
        LDS_BARRIER();                                                         \
    }

    for (int t2 = 0; t2 < T_; t2 += 2) {
        STEP(t2, 0, 1)
        STEP(t2 + 1, 1, 0)
    }
#undef STEP
}

extern "C" void kernel_launch(void* const* d_in, const int* in_sizes, int n_in,
                              void* d_out, int out_size, void* d_ws, size_t ws_size,
                              hipStream_t stream) {
    const float* x    = (const float*)d_in[0];
    const float* z    = (const float*)d_in[1];
    const float* h0   = (const float*)d_in[2];
    const float* W_x  = (const float*)d_in[3];
    const float* W_h  = (const float*)d_in[4];
    const float* bias = (const float*)d_in[5];
    const float* C    = (const float*)d_in[6];

    float* outputs = (float*)d_out;                     // [T*B*D]
    float* h_out   = outputs + (size_t)T_ * B_ * D_;    // [(T+1)*B*S*D]

    float*  WxT = (float*)d_ws;                         // D*D floats
    float2* wz  = (float2*)(WxT + D_ * D_);             // T*B*D float2

    hipMemsetAsync(outputs, 0, (size_t)T_ * B_ * D_ * sizeof(float), stream);
    k_transpose<<<64, 1024, 0, stream>>>(W_x, WxT);
    k_wxall<<<T_ * B_ / 16, 256, 0, stream>>>(x, z, WxT, bias, wz);
    k_rec<<<B_ * S_ / 4, 512, 0, stream>>>(W_h, wz, h0, C, outputs, h_out);
}